// Round 6
// baseline (181.610 us; speedup 1.0000x reference)
//
#include <hip/hip_runtime.h>
#include <hip/hip_bf16.h>

// Problem constants (from reference)
constexpr int B = 8;
constexpr int L = 2048;
constexpr int ANG = 16;
constexpr int AMP = 48;
constexpr int H = 4;
constexpr int AQK = 12, GQK = 6;
constexpr int AV = 12, GV = 6;
constexpr int HD = 2 * GQK + AQK;      // 24
constexpr int LOOKBACK = 100;
constexpr int NTOK = B * L;            // 16384

// ---------------- Fused kernel: QKV projection + banded attention (v2) ----------------
// Block = (b, h, 64-query tile), 256 threads.
// Phase B: threads 0..nrows-1 compute k,v for row (kmin+tid); threads 192..255
//          compute q for query rows. x loaded global->regs (no LDS staging);
//          i-outer accumulation => weight addresses wave-uniform (s_load) and
//          VALU ~= MAC count. Threads nrows..162 zero-fill unused tile rows.
// Phase B2: K/V into XOR-swizzled [163][8] float4 tiles (slot = s ^ (r&7));
//          Q into [64][7]-padded tile (stride 112B, conflict-free).
// Phase C: 4-group parity split-K, TWO-PASS softmax: 25 scores in regs ->
//          tree max -> exp+sum -> p*V accumulate. No serial exp chain.
//          Merge via Po[4][64][7] (112B stride, conflict-free), (m,s) in slot 6.
constexpr int TQ     = 64;
constexpr int GROUPS = 4;
constexpr int CHUNK  = 25;                 // ceil(LOOKBACK/GROUPS)
constexpr int MAXK   = TQ + LOOKBACK - 1;  // 163
constexpr int NT     = L / TQ;             // 32

__global__ __launch_bounds__(256) void fused_qkv_attn2_kernel(
    const float* __restrict__ x_ang, const float* __restrict__ x_amp,
    const float* __restrict__ Wq_amp, const float* __restrict__ Wk_amp,
    const float* __restrict__ Wv_amp,
    const float* __restrict__ Wq_ang_r, const float* __restrict__ Wq_ang_i,
    const float* __restrict__ Wk_ang_r, const float* __restrict__ Wk_ang_i,
    const float* __restrict__ Wv_ang_r, const float* __restrict__ Wv_ang_i,
    float* __restrict__ att)
{
    __shared__ float4 Ks[MAXK][8];
    __shared__ float4 Vs[MAXK][8];
    __shared__ float4 Qs[TQ][7];
    __shared__ float4 Po[GROUPS][TQ][7];   // slot 6 = (m, s, 0, 0)

    const int tid = threadIdx.x;
    const int bh  = blockIdx.x / NT;
    const int qt  = blockIdx.x % NT;
    const int b   = bh / H, h = bh % H;
    const int q0  = qt * TQ;
    int kmin = q0 - (LOOKBACK - 1); if (kmin < 0) kmin = 0;
    const int nrows = q0 + TQ - kmin;      // <= 163

    // ---------------- Phase B: projections (global x -> regs, i-outer) ----------------
    const bool kvact = (tid < nrows);
    const bool qact  = (tid >= 192);
    const int  qrow  = tid - 192;

    float4 kpack[6], vpack[6], qpack[6];

    if (kvact) {
        const int row = kmin + tid;
        float xm[48], xr[16], xi[16];
        {
            const float4* xm4 = (const float4*)(x_amp + ((size_t)b * L + row) * AMP);
            #pragma unroll
            for (int i = 0; i < 12; ++i) {
                float4 t = xm4[i];
                xm[4*i+0]=t.x; xm[4*i+1]=t.y; xm[4*i+2]=t.z; xm[4*i+3]=t.w;
            }
            const float4* xg4 = (const float4*)(x_ang + ((size_t)b * L + row) * (2*ANG));
            #pragma unroll
            for (int i = 0; i < 4; ++i) {
                float4 t = xg4[i];
                xr[4*i+0]=t.x; xr[4*i+1]=t.y; xr[4*i+2]=t.z; xr[4*i+3]=t.w;
                float4 u = xg4[4+i];
                xi[4*i+0]=u.x; xi[4*i+1]=u.y; xi[4*i+2]=u.z; xi[4*i+3]=u.w;
            }
        }
        float ka[12], va[12], kr[6], ki[6], vr[6], vi[6];
        #pragma unroll
        for (int c = 0; c < 12; ++c) { ka[c]=0.f; va[c]=0.f; }
        #pragma unroll
        for (int c = 0; c < 6; ++c) { kr[c]=0.f; ki[c]=0.f; vr[c]=0.f; vi[c]=0.f; }

        #pragma unroll
        for (int i = 0; i < AMP; ++i) {           // amp: wave-uniform weight rows
            const float* wk = Wk_amp + i * 48 + h * AQK;
            const float* wv = Wv_amp + i * 48 + h * AQK;
            float x = xm[i];
            #pragma unroll
            for (int c = 0; c < 12; ++c) {
                ka[c] += x * wk[c];
                va[c] += x * wv[c];
            }
        }
        #pragma unroll
        for (int i = 0; i < ANG; ++i) {           // ang complex
            const float* wkr = Wk_ang_r + i * 24 + h * GQK;
            const float* wki = Wk_ang_i + i * 24 + h * GQK;
            const float* wvr = Wv_ang_r + i * 24 + h * GQK;
            const float* wvi = Wv_ang_i + i * 24 + h * GQK;
            float a = xr[i], bb = xi[i];
            #pragma unroll
            for (int c = 0; c < 6; ++c) {
                kr[c] += a * wkr[c] - bb * wki[c];
                ki[c] += a * wki[c] + bb * wkr[c];
                vr[c] += a * wvr[c] - bb * wvi[c];
                vi[c] += a * wvi[c] + bb * wvr[c];
            }
        }
        kpack[0] = make_float4(kr[0],kr[1],kr[2],kr[3]);
        kpack[1] = make_float4(kr[4],kr[5],ki[0],ki[1]);
        kpack[2] = make_float4(ki[2],ki[3],ki[4],ki[5]);
        kpack[3] = make_float4(ka[0],ka[1],ka[2],ka[3]);
        kpack[4] = make_float4(ka[4],ka[5],ka[6],ka[7]);
        kpack[5] = make_float4(ka[8],ka[9],ka[10],ka[11]);
        vpack[0] = make_float4(vr[0],vr[1],vr[2],vr[3]);
        vpack[1] = make_float4(vr[4],vr[5],vi[0],vi[1]);
        vpack[2] = make_float4(vi[2],vi[3],vi[4],vi[5]);
        vpack[3] = make_float4(va[0],va[1],va[2],va[3]);
        vpack[4] = make_float4(va[4],va[5],va[6],va[7]);
        vpack[5] = make_float4(va[8],va[9],va[10],va[11]);
    }
    if (qact) {
        const int row = q0 + qrow;
        float xm[48], xr[16], xi[16];
        {
            const float4* xm4 = (const float4*)(x_amp + ((size_t)b * L + row) * AMP);
            #pragma unroll
            for (int i = 0; i < 12; ++i) {
                float4 t = xm4[i];
                xm[4*i+0]=t.x; xm[4*i+1]=t.y; xm[4*i+2]=t.z; xm[4*i+3]=t.w;
            }
            const float4* xg4 = (const float4*)(x_ang + ((size_t)b * L + row) * (2*ANG));
            #pragma unroll
            for (int i = 0; i < 4; ++i) {
                float4 t = xg4[i];
                xr[4*i+0]=t.x; xr[4*i+1]=t.y; xr[4*i+2]=t.z; xr[4*i+3]=t.w;
                float4 u = xg4[4+i];
                xi[4*i+0]=u.x; xi[4*i+1]=u.y; xi[4*i+2]=u.z; xi[4*i+3]=u.w;
            }
        }
        float qa[12], qrr[6], qii[6];
        #pragma unroll
        for (int c = 0; c < 12; ++c) qa[c]=0.f;
        #pragma unroll
        for (int c = 0; c < 6; ++c) { qrr[c]=0.f; qii[c]=0.f; }

        #pragma unroll
        for (int i = 0; i < AMP; ++i) {
            const float* wq = Wq_amp + i * 48 + h * AQK;
            float x = xm[i];
            #pragma unroll
            for (int c = 0; c < 12; ++c) qa[c] += x * wq[c];
        }
        #pragma unroll
        for (int i = 0; i < ANG; ++i) {
            const float* wr = Wq_ang_r + i * 24 + h * GQK;
            const float* wi = Wq_ang_i + i * 24 + h * GQK;
            float a = xr[i], bb = xi[i];
            #pragma unroll
            for (int c = 0; c < 6; ++c) {
                qrr[c] += a * wr[c] - bb * wi[c];
                qii[c] += a * wi[c] + bb * wr[c];
            }
        }
        qpack[0] = make_float4(qrr[0],qrr[1],qrr[2],qrr[3]);
        qpack[1] = make_float4(qrr[4],qrr[5],qii[0],qii[1]);
        qpack[2] = make_float4(qii[2],qii[3],qii[4],qii[5]);
        qpack[3] = make_float4(qa[0],qa[1],qa[2],qa[3]);
        qpack[4] = make_float4(qa[4],qa[5],qa[6],qa[7]);
        qpack[5] = make_float4(qa[8],qa[9],qa[10],qa[11]);
    }

    // ---------------- Phase B2: write tiles ----------------
    if (kvact) {
        int r = tid, rx = r & 7;
        #pragma unroll
        for (int s = 0; s < 6; ++s) {
            Ks[r][s ^ rx] = kpack[s];
            Vs[r][s ^ rx] = vpack[s];
        }
    } else if (tid < MAXK) {               // zero-fill unwritten rows (early tiles)
        float4 z = make_float4(0.f,0.f,0.f,0.f);
        #pragma unroll
        for (int s = 0; s < 6; ++s) { Ks[tid][s] = z; Vs[tid][s] = z; }
    }
    if (qact) {
        #pragma unroll
        for (int s = 0; s < 6; ++s) Qs[qrow][s] = qpack[s];
    }
    __syncthreads();

    // ---------------- Phase C: two-pass split-K softmax ----------------
    const int ql = tid & (TQ - 1);
    const int g  = tid >> 6;               // 0..3
    const int qi = q0 + ql;

    float4 q4[6];
    #pragma unroll
    for (int s = 0; s < 6; ++s) q4[s] = Qs[ql][s];

    const float scale = 0.2041241452319315f; // 1/sqrt(24)
    int j0 = qi - (LOOKBACK - 1); if (j0 < 0) j0 = 0;
    const int jstart = j0 + g;

    float sc[CHUNK];
    #pragma unroll
    for (int t = 0; t < CHUNK; ++t) {
        int j  = jstart + t * GROUPS;
        int r  = j - kmin;
        int rx = r & 7;
        float d = 0.f;
        #pragma unroll
        for (int s = 0; s < 6; ++s) {
            float4 kk = Ks[r][s ^ rx];
            d += q4[s].x*kk.x + q4[s].y*kk.y + q4[s].z*kk.z + q4[s].w*kk.w;
        }
        sc[t] = (j <= qi) ? d * scale : -3.0e38f;
    }
    float m = sc[0];
    #pragma unroll
    for (int t = 1; t < CHUNK; ++t) m = fmaxf(m, sc[t]);
    float ssum = 0.f;
    #pragma unroll
    for (int t = 0; t < CHUNK; ++t) {
        float p = __expf(sc[t] - m);
        p = (sc[t] > -1.0e37f) ? p : 0.f;
        sc[t] = p;
        ssum += p;
    }
    float4 o[6];
    #pragma unroll
    for (int s = 0; s < 6; ++s) o[s] = make_float4(0.f,0.f,0.f,0.f);
    #pragma unroll
    for (int t = 0; t < CHUNK; ++t) {
        float p  = sc[t];
        int j    = jstart + t * GROUPS;
        int r    = j - kmin;
        int rx   = r & 7;
        #pragma unroll
        for (int s = 0; s < 6; ++s) {
            float4 vv = Vs[r][s ^ rx];   // zero-filled rows -> no NaN
            o[s].x += p * vv.x; o[s].y += p * vv.y;
            o[s].z += p * vv.z; o[s].w += p * vv.w;
        }
    }

    #pragma unroll
    for (int s = 0; s < 6; ++s) Po[g][ql][s] = o[s];
    Po[g][ql][6] = make_float4(m, ssum, 0.f, 0.f);
    __syncthreads();

    // ---------------- merge + write att (token-major [tok][h*24+d]) ----------------
    {
        int qq    = tid & 63;
        int chunk = tid >> 6;
        float4 ms0 = Po[0][qq][6], ms1 = Po[1][qq][6];
        float4 ms2 = Po[2][qq][6], ms3 = Po[3][qq][6];
        float mm = fmaxf(fmaxf(ms0.x, ms1.x), fmaxf(ms2.x, ms3.x));
        float c0 = __expf(ms0.x - mm), c1 = __expf(ms1.x - mm);
        float c2 = __expf(ms2.x - mm), c3 = __expf(ms3.x - mm);
        float inv = 1.f / (ms0.y*c0 + ms1.y*c1 + ms2.y*c2 + ms3.y*c3);

        float4* dst = (float4*)att + (size_t)(b * L + q0 + qq) * 24 + h * 6;

        int s = chunk;
        {
            float4 a0 = Po[0][qq][s], a1 = Po[1][qq][s], a2 = Po[2][qq][s], a3 = Po[3][qq][s];
            float4 acc;
            acc.x = (a0.x*c0 + a1.x*c1 + a2.x*c2 + a3.x*c3) * inv;
            acc.y = (a0.y*c0 + a1.y*c1 + a2.y*c2 + a3.y*c3) * inv;
            acc.z = (a0.z*c0 + a1.z*c1 + a2.z*c2 + a3.z*c3) * inv;
            acc.w = (a0.w*c0 + a1.w*c1 + a2.w*c2 + a3.w*c3) * inv;
            dst[s] = acc;
        }
        if (chunk < 2) {
            s = chunk + 4;
            float4 a0 = Po[0][qq][s], a1 = Po[1][qq][s], a2 = Po[2][qq][s], a3 = Po[3][qq][s];
            float4 acc;
            acc.x = (a0.x*c0 + a1.x*c1 + a2.x*c2 + a3.x*c3) * inv;
            acc.y = (a0.y*c0 + a1.y*c1 + a2.y*c2 + a3.y*c3) * inv;
            acc.z = (a0.z*c0 + a1.z*c1 + a2.z*c2 + a3.z*c3) * inv;
            acc.w = (a0.w*c0 + a1.w*c1 + a2.w*c2 + a3.w*c3) * inv;
            dst[s] = acc;
        }
    }
}

// ---------------- Kernel 2: output projections (4 outputs per thread) ----------------
constexpr int PJ_AMP_BLOCKS = (NTOK * 12) / 256;   // 768
constexpr int PJ_ANG_BLOCKS = (NTOK * 4) / 256;    // 256

__global__ __launch_bounds__(256) void proj4_kernel(
    const float* __restrict__ att,
    const float* __restrict__ Wout_amp, const float* __restrict__ bout_amp,
    const float* __restrict__ Wout_ang_r, const float* __restrict__ Wout_ang_i,
    float* __restrict__ out)
{
    constexpr size_t ANG_OUT = (size_t)NTOK * ANG; // 262144
    int bid = blockIdx.x;

    if (bid < PJ_AMP_BLOCKS) {
        int gidx = bid * 256 + threadIdx.x;
        int c4   = (gidx % 12) * 4;     // 0..44
        int tok  = gidx / 12;
        const float4* at4 = (const float4*)att + (size_t)tok * 24;

        float a[48];
        #pragma unroll
        for (int h = 0; h < H; ++h) {
            #pragma unroll
            for (int i = 0; i < 3; ++i) {
                float4 t = at4[h * 6 + 3 + i];
                a[h*12 + 4*i+0]=t.x; a[h*12 + 4*i+1]=t.y;
                a[h*12 + 4*i+2]=t.z; a[h*12 + 4*i+3]=t.w;
            }
        }
        float4 acc = *(const float4*)(bout_amp + c4);
        #pragma unroll
        for (int i = 0; i < 48; ++i) {
            float4 w = *(const float4*)(Wout_amp + i * 48 + c4);
            acc.x += a[i]*w.x; acc.y += a[i]*w.y; acc.z += a[i]*w.z; acc.w += a[i]*w.w;
        }
        *(float4*)(out + 2*ANG_OUT + (size_t)tok * 48 + c4) = acc;
    } else {
        int gidx = (bid - PJ_AMP_BLOCKS) * 256 + threadIdx.x;
        int c4   = (gidx % 4) * 4;      // 0,4,8,12
        int tok  = gidx / 4;
        const float4* at4 = (const float4*)att + (size_t)tok * 24;

        float ar[24], ai[24];
        #pragma unroll
        for (int h = 0; h < H; ++h) {
            float4 t0 = at4[h*6+0], t1 = at4[h*6+1], t2 = at4[h*6+2];
            ar[h*6+0]=t0.x; ar[h*6+1]=t0.y; ar[h*6+2]=t0.z; ar[h*6+3]=t0.w;
            ar[h*6+4]=t1.x; ar[h*6+5]=t1.y;
            ai[h*6+0]=t1.z; ai[h*6+1]=t1.w;
            ai[h*6+2]=t2.x; ai[h*6+3]=t2.y; ai[h*6+4]=t2.z; ai[h*6+5]=t2.w;
        }
        float4 accr = make_float4(0.f,0.f,0.f,0.f);
        float4 acci = make_float4(0.f,0.f,0.f,0.f);
        #pragma unroll
        for (int i = 0; i < 24; ++i) {
            float4 wr = *(const float4*)(Wout_ang_r + i * 16 + c4);
            float4 wi = *(const float4*)(Wout_ang_i + i * 16 + c4);
            float r = ar[i], im = ai[i];
            accr.x += r*wr.x - im*wi.x;  accr.y += r*wr.y - im*wi.y;
            accr.z += r*wr.z - im*wi.z;  accr.w += r*wr.w - im*wi.w;
            acci.x += r*wi.x + im*wr.x;  acci.y += r*wi.y + im*wr.y;
            acci.z += r*wi.z + im*wr.z;  acci.w += r*wi.w + im*wr.w;
        }
        *(float4*)(out + (size_t)tok * 16 + c4)           = accr;
        *(float4*)(out + ANG_OUT + (size_t)tok * 16 + c4) = acci;
    }
}

// -------------------- Launch --------------------
extern "C" void kernel_launch(void* const* d_in, const int* in_sizes, int n_in,
                              void* d_out, int out_size, void* d_ws, size_t ws_size,
                              hipStream_t stream)
{
    const float* x_ang      = (const float*)d_in[0];
    const float* x_amp      = (const float*)d_in[1];
    const float* Wq_amp     = (const float*)d_in[2];
    const float* Wk_amp     = (const float*)d_in[3];
    const float* Wv_amp     = (const float*)d_in[4];
    const float* Wq_ang_r   = (const float*)d_in[5];
    const float* Wq_ang_i   = (const float*)d_in[6];
    const float* Wk_ang_r   = (const float*)d_in[7];
    const float* Wk_ang_i   = (const float*)d_in[8];
    const float* Wv_ang_r   = (const float*)d_in[9];
    const float* Wv_ang_i   = (const float*)d_in[10];
    const float* Wout_amp   = (const float*)d_in[11];
    const float* bout_amp   = (const float*)d_in[12];
    const float* Wout_ang_r = (const float*)d_in[13];
    const float* Wout_ang_i = (const float*)d_in[14];

    float* out = (float*)d_out;
    float* att = (float*)d_ws;   // NTOK * 96 floats = 6.29 MB, token-major

    fused_qkv_attn2_kernel<<<B * H * NT, 256, 0, stream>>>(
        x_ang, x_amp, Wq_amp, Wk_amp, Wv_amp,
        Wq_ang_r, Wq_ang_i, Wk_ang_r, Wk_ang_i, Wv_ang_r, Wv_ang_i,
        att);

    proj4_kernel<<<PJ_AMP_BLOCKS + PJ_ANG_BLOCKS, 256, 0, stream>>>(
        att, Wout_amp, bout_amp, Wout_ang_r, Wout_ang_i, out);
}

// Round 7
// 149.455 us; speedup vs baseline: 1.2151x; 1.2151x over previous
//
#include <hip/hip_runtime.h>
#include <hip/hip_bf16.h>

// Problem constants (from reference)
constexpr int B = 8;
constexpr int L = 2048;
constexpr int ANG = 16;
constexpr int AMP = 48;
constexpr int H = 4;
constexpr int AQK = 12, GQK = 6;
constexpr int AV = 12, GV = 6;
constexpr int HD = 2 * GQK + AQK;      // 24
constexpr int LOOKBACK = 100;
constexpr int NTOK = B * L;            // 16384

// ---------------- Fused kernel: QKV projection + banded attention (v3) ----------------
// Block = (b, h, 64-query tile), 256 threads = 4 waves.
// Phase A: coalesced stage of x rows [kmin, q0+63] into LDS (R5-proven).
// Phase B: threads 0..nrows-1 -> k,v row (kmin+tid); threads 192..255 -> q rows.
//          s-outer passes, wave-uniform weight addresses (R5-proven, 88 VGPR).
// Phase B2: K/V -> XOR-swizzled [163][8] float4 tiles; Q -> [64][7] tile.
//          Tiles UNION the stage memory (53.5 KB total -> 3 blocks/CU).
// Phase C: wave = 16 queries x 4 split-K groups (lane = g*16+q16).
//          Two-pass softmax over 25 keys/lane (scores in regs, tree max, no
//          serial exp chain). Merge across groups via __shfl_xor(16|32) -
//          NO LDS merge arrays, no extra barrier.
constexpr int TQ     = 64;
constexpr int GROUPS = 4;
constexpr int CHUNK  = 25;                 // ceil(LOOKBACK/GROUPS)
constexpr int MAXK   = TQ + LOOKBACK - 1;  // 163
constexpr int NT     = L / TQ;             // 32

struct StageT {
    float xam[MAXK][49];   // x_amp rows, stride 49 (odd -> conflict-free column reads)
    float xan[MAXK][33];   // x_ang rows (16 real + 16 imag), stride 33
};
struct TileT {
    float4 Ks[MAXK][8];    // swizzled: row r, slot s^(r&7)
    float4 Vs[MAXK][8];
    float4 Qs[TQ][7];      // stride 112B
};
union SharedU { StageT stage; TileT t; };  // 53464 B -> 3 blocks/CU

__global__ __launch_bounds__(256, 3) void fused_qkv_attn3_kernel(
    const float* __restrict__ x_ang, const float* __restrict__ x_amp,
    const float* __restrict__ Wq_amp, const float* __restrict__ Wk_amp,
    const float* __restrict__ Wv_amp,
    const float* __restrict__ Wq_ang_r, const float* __restrict__ Wq_ang_i,
    const float* __restrict__ Wk_ang_r, const float* __restrict__ Wk_ang_i,
    const float* __restrict__ Wv_ang_r, const float* __restrict__ Wv_ang_i,
    float* __restrict__ att)
{
    __shared__ SharedU u;

    const int tid = threadIdx.x;
    const int bh  = blockIdx.x / NT;
    const int qt  = blockIdx.x % NT;
    const int b   = bh / H, h = bh % H;
    const int q0  = qt * TQ;
    int kmin = q0 - (LOOKBACK - 1); if (kmin < 0) kmin = 0;
    const int nrows = q0 + TQ - kmin;      // <= 163
    const int qoff  = q0 - kmin;

    // ---------------- Phase A: coalesced stage of x ----------------
    {
        const float4* xm4 = (const float4*)(x_amp + ((size_t)b * L + kmin) * AMP);
        const float4* xg4 = (const float4*)(x_ang + ((size_t)b * L + kmin) * (2 * ANG));
        int namp = nrows * 12;
        int ntot = namp + nrows * 8;
        for (int c = tid; c < ntot; c += 256) {
            if (c < namp) {
                int r = c / 12, i = c % 12;
                float4 t = xm4[c];
                float* p = &u.stage.xam[r][4 * i];
                p[0] = t.x; p[1] = t.y; p[2] = t.z; p[3] = t.w;
            } else {
                int c2 = c - namp;
                int r = c2 / 8, i = c2 % 8;
                float4 t = xg4[c2];
                float* p = &u.stage.xan[r][4 * i];
                p[0] = t.x; p[1] = t.y; p[2] = t.z; p[3] = t.w;
            }
        }
    }
    __syncthreads();

    // ---------------- Phase B: projections into registers (R5 form) ----------------
    float4 kpack[6], vpack[6], qpack[6];
    const bool kvact = (tid < nrows);
    const bool qact  = (tid >= 192);
    const int  qrow  = tid - 192;

    #pragma unroll
    for (int s = 0; s < 6; ++s) {
        if (kvact) {
            int r = tid;
            if (s >= 3) {
                int col4 = h * AQK + (s - 3) * 4;
                const float* Wk = Wk_amp + col4;
                const float* Wv = Wv_amp + col4;
                float4 ka = {0,0,0,0}, va = {0,0,0,0};
                #pragma unroll
                for (int i = 0; i < AMP; ++i) {
                    float x = u.stage.xam[r][i];
                    float4 wk = *(const float4*)(Wk + i * 48);
                    float4 wv = *(const float4*)(Wv + i * 48);
                    ka.x += x * wk.x; ka.y += x * wk.y; ka.z += x * wk.z; ka.w += x * wk.w;
                    va.x += x * wv.x; va.y += x * wv.y; va.z += x * wv.z; va.w += x * wv.w;
                }
                kpack[s] = ka; vpack[s] = va;
            } else {
                float kk[4], vv[4];
                #pragma unroll
                for (int c = 0; c < 4; ++c) {
                    int d = 4 * s + c;                 // 0..11
                    bool re = (d < GQK);
                    int dd = re ? d : d - GQK;
                    int col = h * GQK + dd;
                    const float* WkA = re ? Wk_ang_r : Wk_ang_i;
                    const float* WkB = re ? Wk_ang_i : Wk_ang_r;
                    const float* WvA = re ? Wv_ang_r : Wv_ang_i;
                    const float* WvB = re ? Wv_ang_i : Wv_ang_r;
                    float sgn = re ? -1.f : 1.f;
                    float ak = 0, bk = 0, aw = 0, bw = 0;
                    #pragma unroll
                    for (int i = 0; i < ANG; ++i) {
                        float xr = u.stage.xan[r][i];
                        float xi = u.stage.xan[r][16 + i];
                        ak += xr * WkA[i * 24 + col];  bk += xi * WkB[i * 24 + col];
                        aw += xr * WvA[i * 24 + col];  bw += xi * WvB[i * 24 + col];
                    }
                    kk[c] = ak + sgn * bk;  vv[c] = aw + sgn * bw;
                }
                kpack[s] = make_float4(kk[0], kk[1], kk[2], kk[3]);
                vpack[s] = make_float4(vv[0], vv[1], vv[2], vv[3]);
            }
        }
        if (qact) {
            int r = qoff + qrow;
            if (s >= 3) {
                int col4 = h * AQK + (s - 3) * 4;
                const float* Wq = Wq_amp + col4;
                float4 qa = {0,0,0,0};
                #pragma unroll
                for (int i = 0; i < AMP; ++i) {
                    float x = u.stage.xam[r][i];
                    float4 wq = *(const float4*)(Wq + i * 48);
                    qa.x += x * wq.x; qa.y += x * wq.y; qa.z += x * wq.z; qa.w += x * wq.w;
                }
                qpack[s] = qa;
            } else {
                float qq[4];
                #pragma unroll
                for (int c = 0; c < 4; ++c) {
                    int d = 4 * s + c;
                    bool re = (d < GQK);
                    int dd = re ? d : d - GQK;
                    int col = h * GQK + dd;
                    const float* WA = re ? Wq_ang_r : Wq_ang_i;
                    const float* WB = re ? Wq_ang_i : Wq_ang_r;
                    float sgn = re ? -1.f : 1.f;
                    float aa = 0, bb = 0;
                    #pragma unroll
                    for (int i = 0; i < ANG; ++i) {
                        float xr = u.stage.xan[r][i];
                        float xi = u.stage.xan[r][16 + i];
                        aa += xr * WA[i * 24 + col];  bb += xi * WB[i * 24 + col];
                    }
                    qq[c] = aa + sgn * bb;
                }
                qpack[s] = make_float4(qq[0], qq[1], qq[2], qq[3]);
            }
        }
    }
    __syncthreads();   // all stage reads complete (union about to be overwritten)

    // ---------------- Phase B2: write tiles ----------------
    if (kvact) {
        int r = tid, rx = r & 7;
        #pragma unroll
        for (int s = 0; s < 6; ++s) {
            u.t.Ks[r][s ^ rx] = kpack[s];
            u.t.Vs[r][s ^ rx] = vpack[s];
        }
    } else if (tid < MAXK) {               // zero-fill rows [nrows, MAXK) (early tiles)
        float4 z = make_float4(0.f,0.f,0.f,0.f);
        #pragma unroll
        for (int s = 0; s < 6; ++s) { u.t.Ks[tid][s] = z; u.t.Vs[tid][s] = z; }
    }
    if (qact) {
        #pragma unroll
        for (int s = 0; s < 6; ++s) u.t.Qs[qrow][s] = qpack[s];
    }
    __syncthreads();

    // ---------------- Phase C: two-pass split-K softmax, groups within wave ----------------
    const int lane = tid & 63;
    const int w    = tid >> 6;             // wave id 0..3 -> queries w*16..w*16+15
    const int q16  = lane & 15;
    const int g    = lane >> 4;            // split-K group 0..3
    const int ql   = w * 16 + q16;
    const int qi   = q0 + ql;

    float4 q4[6];
    #pragma unroll
    for (int s = 0; s < 6; ++s) q4[s] = u.t.Qs[ql][s];

    const float scale = 0.2041241452319315f; // 1/sqrt(24)
    int j0 = qi - (LOOKBACK - 1); if (j0 < 0) j0 = 0;
    const int jstart = j0 + g;

    float sc[CHUNK];
    #pragma unroll
    for (int t = 0; t < CHUNK; ++t) {
        int j  = jstart + t * GROUPS;
        int r  = j - kmin;
        int rx = r & 7;
        float d = 0.f;
        #pragma unroll
        for (int s = 0; s < 6; ++s) {
            float4 kk = u.t.Ks[r][s ^ rx];
            d += q4[s].x*kk.x + q4[s].y*kk.y + q4[s].z*kk.z + q4[s].w*kk.w;
        }
        sc[t] = (j <= qi) ? d * scale : -3.0e38f;
    }
    float m = sc[0];
    #pragma unroll
    for (int t = 1; t < CHUNK; ++t) m = fmaxf(m, sc[t]);
    float ssum = 0.f;
    #pragma unroll
    for (int t = 0; t < CHUNK; ++t) {
        float p = __expf(sc[t] - m);
        p = (sc[t] > -1.0e37f) ? p : 0.f;
        sc[t] = p;
        ssum += p;
    }
    float4 o[6];
    #pragma unroll
    for (int s = 0; s < 6; ++s) o[s] = make_float4(0.f,0.f,0.f,0.f);
    #pragma unroll
    for (int t = 0; t < CHUNK; ++t) {
        float p  = sc[t];
        int j    = jstart + t * GROUPS;
        int r    = j - kmin;
        int rx   = r & 7;
        #pragma unroll
        for (int s = 0; s < 6; ++s) {
            float4 vv = u.t.Vs[r][s ^ rx];
            o[s].x += p * vv.x; o[s].y += p * vv.y;
            o[s].z += p * vv.z; o[s].w += p * vv.w;
        }
    }

    // merge across the 4 groups (lanes xor 16, xor 32) — exact algebra
    #pragma unroll
    for (int d = 16; d <= 32; d <<= 1) {
        float m2 = __shfl_xor(m, d);
        float s2 = __shfl_xor(ssum, d);
        float mm = fmaxf(m, m2);
        float c1 = __expf(m - mm);
        float c2 = __expf(m2 - mm);
        ssum = ssum * c1 + s2 * c2;
        #pragma unroll
        for (int s = 0; s < 6; ++s) {
            o[s].x = o[s].x * c1 + __shfl_xor(o[s].x, d) * c2;
            o[s].y = o[s].y * c1 + __shfl_xor(o[s].y, d) * c2;
            o[s].z = o[s].z * c1 + __shfl_xor(o[s].z, d) * c2;
            o[s].w = o[s].w * c1 + __shfl_xor(o[s].w, d) * c2;
        }
        m = mm;
    }
    float inv = 1.f / ssum;

    // write att token-major [tok][h*24+d]; 4 duplicate lanes split the 6 slots
    {
        float4* dst = (float4*)att + (size_t)(b * L + qi) * 24 + h * 6;
        if (g == 0) {
            dst[0] = make_float4(o[0].x*inv, o[0].y*inv, o[0].z*inv, o[0].w*inv);
            dst[4] = make_float4(o[4].x*inv, o[4].y*inv, o[4].z*inv, o[4].w*inv);
        } else if (g == 1) {
            dst[1] = make_float4(o[1].x*inv, o[1].y*inv, o[1].z*inv, o[1].w*inv);
            dst[5] = make_float4(o[5].x*inv, o[5].y*inv, o[5].z*inv, o[5].w*inv);
        } else if (g == 2) {
            dst[2] = make_float4(o[2].x*inv, o[2].y*inv, o[2].z*inv, o[2].w*inv);
        } else {
            dst[3] = make_float4(o[3].x*inv, o[3].y*inv, o[3].z*inv, o[3].w*inv);
        }
    }
}

// ---------------- Kernel 2: output projections (4 outputs per thread) ----------------
constexpr int PJ_AMP_BLOCKS = (NTOK * 12) / 256;   // 768
constexpr int PJ_ANG_BLOCKS = (NTOK * 4) / 256;    // 256

__global__ __launch_bounds__(256) void proj4_kernel(
    const float* __restrict__ att,
    const float* __restrict__ Wout_amp, const float* __restrict__ bout_amp,
    const float* __restrict__ Wout_ang_r, const float* __restrict__ Wout_ang_i,
    float* __restrict__ out)
{
    constexpr size_t ANG_OUT = (size_t)NTOK * ANG; // 262144
    int bid = blockIdx.x;

    if (bid < PJ_AMP_BLOCKS) {
        int gidx = bid * 256 + threadIdx.x;
        int c4   = (gidx % 12) * 4;     // 0..44
        int tok  = gidx / 12;
        const float4* at4 = (const float4*)att + (size_t)tok * 24;

        float a[48];
        #pragma unroll
        for (int h = 0; h < H; ++h) {
            #pragma unroll
            for (int i = 0; i < 3; ++i) {
                float4 t = at4[h * 6 + 3 + i];
                a[h*12 + 4*i+0]=t.x; a[h*12 + 4*i+1]=t.y;
                a[h*12 + 4*i+2]=t.z; a[h*12 + 4*i+3]=t.w;
            }
        }
        float4 acc = *(const float4*)(bout_amp + c4);
        #pragma unroll
        for (int i = 0; i < 48; ++i) {
            float4 w = *(const float4*)(Wout_amp + i * 48 + c4);
            acc.x += a[i]*w.x; acc.y += a[i]*w.y; acc.z += a[i]*w.z; acc.w += a[i]*w.w;
        }
        *(float4*)(out + 2*ANG_OUT + (size_t)tok * 48 + c4) = acc;
    } else {
        int gidx = (bid - PJ_AMP_BLOCKS) * 256 + threadIdx.x;
        int c4   = (gidx % 4) * 4;      // 0,4,8,12
        int tok  = gidx / 4;
        const float4* at4 = (const float4*)att + (size_t)tok * 24;

        float ar[24], ai[24];
        #pragma unroll
        for (int h = 0; h < H; ++h) {
            float4 t0 = at4[h*6+0], t1 = at4[h*6+1], t2 = at4[h*6+2];
            ar[h*6+0]=t0.x; ar[h*6+1]=t0.y; ar[h*6+2]=t0.z; ar[h*6+3]=t0.w;
            ar[h*6+4]=t1.x; ar[h*6+5]=t1.y;
            ai[h*6+0]=t1.z; ai[h*6+1]=t1.w;
            ai[h*6+2]=t2.x; ai[h*6+3]=t2.y; ai[h*6+4]=t2.z; ai[h*6+5]=t2.w;
        }
        float4 accr = make_float4(0.f,0.f,0.f,0.f);
        float4 acci = make_float4(0.f,0.f,0.f,0.f);
        #pragma unroll
        for (int i = 0; i < 24; ++i) {
            float4 wr = *(const float4*)(Wout_ang_r + i * 16 + c4);
            float4 wi = *(const float4*)(Wout_ang_i + i * 16 + c4);
            float r = ar[i], im = ai[i];
            accr.x += r*wr.x - im*wi.x;  accr.y += r*wr.y - im*wi.y;
            accr.z += r*wr.z - im*wi.z;  accr.w += r*wr.w - im*wi.w;
            acci.x += r*wi.x + im*wr.x;  acci.y += r*wi.y + im*wr.y;
            acci.z += r*wi.z + im*wr.z;  acci.w += r*wi.w + im*wr.w;
        }
        *(float4*)(out + (size_t)tok * 16 + c4)           = accr;
        *(float4*)(out + ANG_OUT + (size_t)tok * 16 + c4) = acci;
    }
}

// -------------------- Launch --------------------
extern "C" void kernel_launch(void* const* d_in, const int* in_sizes, int n_in,
                              void* d_out, int out_size, void* d_ws, size_t ws_size,
                              hipStream_t stream)
{
    const float* x_ang      = (const float*)d_in[0];
    const float* x_amp      = (const float*)d_in[1];
    const float* Wq_amp     = (const float*)d_in[2];
    const float* Wk_amp     = (const float*)d_in[3];
    const float* Wv_amp     = (const float*)d_in[4];
    const float* Wq_ang_r   = (const float*)d_in[5];
    const float* Wq_ang_i   = (const float*)d_in[6];
    const float* Wk_ang_r   = (const float*)d_in[7];
    const float* Wk_ang_i   = (const float*)d_in[8];
    const float* Wv_ang_r   = (const float*)d_in[9];
    const float* Wv_ang_i   = (const float*)d_in[10];
    const float* Wout_amp   = (const float*)d_in[11];
    const float* bout_amp   = (const float*)d_in[12];
    const float* Wout_ang_r = (const float*)d_in[13];
    const float* Wout_ang_i = (const float*)d_in[14];

    float* out = (float*)d_out;
    float* att = (float*)d_ws;   // NTOK * 96 floats = 6.29 MB, token-major

    fused_qkv_attn3_kernel<<<B * H * NT, 256, 0, stream>>>(
        x_ang, x_amp, Wq_amp, Wk_amp, Wv_amp,
        Wq_ang_r, Wq_ang_i, Wk_ang_r, Wk_ang_i, Wv_ang_r, Wv_ang_i,
        att);

    proj4_kernel<<<PJ_AMP_BLOCKS + PJ_ANG_BLOCKS, 256, 0, stream>>>(
        att, Wout_amp, bout_amp, Wout_ang_r, Wout_ang_i, out);
}